// Round 5
// baseline (199.181 us; speedup 1.0000x reference)
//
#include <hip/hip_runtime.h>
#include <hip/hip_bf16.h>

#define N_CL   50000
#define FEAT   64
#define HID    256
#define KD     256
#define T_SEL  1000
#define NBLK   782                 // ceil(50000/64) clause groups
#define JSPLIT 2                   // hidden-half blocks per clause group
#define JPB    (HID / JSPLIT)      // 128 hidden units per block

#define NQUAD  12500               // N_CL/4 int4/float4 quads per row (exact)
#define PKQ    12800               // padded quad count (10 chunks x 1280)
#define CHUNKQ 1280                // quads per chunk (5120 clauses)
#define NCHUNK 10
#define EVG    14                  // events per group
#define NEG    76                  // 76*14 = 1064 >= 1000; grid 760 blocks

// ws layout (in floats)
#define WK_OFF  0                           // 256*2 folded weights
#define CK_OFF  512                         // 2 bias constants
#define MQ_OFF  514                         // 2 uint max-keys
#define P_OFF   520                         // JSPLIT*2*N_CL partial logits
#define LG_OFF  (P_OFF + JSPLIT * 2 * N_CL) // 2*N_CL final logits f32
#define EPK_OFF (LG_OFF + 2 * N_CL)         // ushort4[2][PKQ] packed exp  (51200 f)
#define LPK_OFF (EPK_OFF + 2 * PKQ * 2)     // ushort4[2][PKQ] packed logit
#define ACC_OFF (LPK_OFF + 2 * PKQ * 2)     // float4[T_SEL][NCHUNK][4]    (160000 f)

__device__ __forceinline__ unsigned fkey(float f) {
    unsigned u = __float_as_uint(f);
    return (u & 0x80000000u) ? ~u : (u | 0x80000000u);   // monotone float->uint
}
__device__ __forceinline__ float finv(unsigned k) {
    unsigned u = (k & 0x80000000u) ? (k ^ 0x80000000u) : ~k;
    return __uint_as_float(u);
}
__device__ __forceinline__ float b2f(unsigned short u) {
    return __uint_as_float(((unsigned)u) << 16);
}
__device__ __forceinline__ unsigned short f2bf(float f) {   // RNE bf16 pack
    unsigned u = __float_as_uint(f);
    return (unsigned short)((u + 0x7FFFu + ((u >> 16) & 1u)) >> 16);
}

// ---------------------------------------------------------------- kernel A
__global__ __launch_bounds__(256) void prep_kernel(
        const float* __restrict__ W2, const float* __restrict__ b2,
        const float* __restrict__ keysW,
        float* __restrict__ wk, float* __restrict__ ck,
        unsigned* __restrict__ mq) {
    __shared__ float sk0[KD], sk1[KD], sb2[KD], red[256];
    int tid = threadIdx.x;
    sk0[tid] = keysW[tid];
    sk1[tid] = keysW[KD + tid];
    sb2[tid] = b2[tid];
    if (tid < 2) mq[tid] = 0u;
    __syncthreads();

    const float* w2r = W2 + (size_t)tid * KD;
    float a0 = 0.f, a1 = 0.f;
    #pragma unroll 4
    for (int k = 0; k < KD; k++) {
        float w = w2r[k];
        a0 = fmaf(w, sk0[k], a0);
        a1 = fmaf(w, sk1[k], a1);
    }
    wk[tid * 2 + 0] = a0;
    wk[tid * 2 + 1] = a1;

    red[tid] = sk0[tid] * sb2[tid];
    __syncthreads();
    for (int s = 128; s > 0; s >>= 1) { if (tid < s) red[tid] += red[tid + s]; __syncthreads(); }
    if (tid == 0) ck[0] = red[0];
    __syncthreads();
    red[tid] = sk1[tid] * sb2[tid];
    __syncthreads();
    for (int s = 128; s > 0; s >>= 1) { if (tid < s) red[tid] += red[tid + s]; __syncthreads(); }
    if (tid == 0) ck[1] = red[0];
}

// ---------------------------------------------------------------- kernel B
// MLP partial logits. k-loop FULLY unrolled so x[] stays in VGPRs (rule #20).
__global__ __launch_bounds__(64, 2) void mlp_kernel(
        const float* __restrict__ X, const float* __restrict__ W1,
        const float* __restrict__ b1, const float* __restrict__ wk,
        float* __restrict__ P) {
    int nb = blockIdx.x >> 1;
    int p  = blockIdx.x & 1;
    int n  = nb * 64 + threadIdx.x;
    int nc = (n < N_CL) ? n : (N_CL - 1);

    float x[FEAT];
    const float4* xp = (const float4*)(X + (size_t)nc * FEAT);
    #pragma unroll
    for (int k4 = 0; k4 < FEAT / 4; k4++) {
        float4 v = xp[k4];
        x[4 * k4 + 0] = v.x; x[4 * k4 + 1] = v.y;
        x[4 * k4 + 2] = v.z; x[4 * k4 + 3] = v.w;
    }

    float l0 = 0.f, l1 = 0.f;
    int j0 = p * JPB;
    for (int jg = 0; jg < JPB; jg += 16) {   // runtime loop: h indexed by u only
        float h[16];
        #pragma unroll
        for (int u = 0; u < 16; u++) h[u] = b1[j0 + jg + u];
        #pragma unroll
        for (int k = 0; k < FEAT; k++) {     // FULL unroll: x[k] static
            const float* w1r = W1 + (size_t)k * HID + j0 + jg;
            float xv = x[k];
            #pragma unroll
            for (int u = 0; u < 16; u++) h[u] = fmaf(xv, w1r[u], h[u]);
        }
        #pragma unroll
        for (int u = 0; u < 16; u++) {
            float hv = fmaxf(h[u], 0.0f);
            l0 = fmaf(hv, wk[(j0 + jg + u) * 2 + 0], l0);
            l1 = fmaf(hv, wk[(j0 + jg + u) * 2 + 1], l1);
        }
    }
    if (n < N_CL) {
        P[((size_t)p * 2 + 0) * N_CL + n] = l0;
        P[((size_t)p * 2 + 1) * N_CL + n] = l1;
    }
}

// ---------------------------------------------------------------- kernel C
__global__ __launch_bounds__(256) void logits_fin(
        const float* __restrict__ P, const float* __restrict__ ck,
        float* __restrict__ lg, unsigned* __restrict__ mq) {
    int n = blockIdx.x * 256 + threadIdx.x;
    float m0 = -1e30f, m1 = -1e30f;
    if (n < N_CL) {
        float l0 = ck[0], l1 = ck[1];
        #pragma unroll
        for (int p = 0; p < JSPLIT; p++) {
            l0 += P[((size_t)p * 2 + 0) * N_CL + n];
            l1 += P[((size_t)p * 2 + 1) * N_CL + n];
        }
        lg[n]        = l0;
        lg[N_CL + n] = l1;
        m0 = l0; m1 = l1;
    }
    for (int off = 32; off; off >>= 1) {
        m0 = fmaxf(m0, __shfl_xor(m0, off));
        m1 = fmaxf(m1, __shfl_xor(m1, off));
    }
    __shared__ float sm0[4], sm1[4];
    int w = threadIdx.x >> 6;
    if ((threadIdx.x & 63) == 0) { sm0[w] = m0; sm1[w] = m1; }
    __syncthreads();
    if (threadIdx.x == 0) {
        m0 = fmaxf(fmaxf(sm0[0], sm0[1]), fmaxf(sm0[2], sm0[3]));
        m1 = fmaxf(fmaxf(sm1[0], sm1[1]), fmaxf(sm1[2], sm1[3]));
        atomicMax(mq + 0, fkey(m0));
        atomicMax(mq + 1, fkey(m1));
    }
}

// ---------------------------------------------------------------- kernel C2
// Pack e=exp(l-M) and l as bf16 quads (400KB total, L2-resident for emain).
__global__ __launch_bounds__(256) void epack_kernel(
        const float* __restrict__ lg, const unsigned* __restrict__ mq,
        ushort4* __restrict__ epk, ushort4* __restrict__ lpk) {
    int quad = blockIdx.x * 256 + threadIdx.x;
    if (quad >= PKQ) return;
    #pragma unroll
    for (int q = 0; q < 2; q++) {
        ushort4 ev = {0, 0, 0, 0}, lv = {0, 0, 0, 0};
        if (quad < NQUAD) {
            float4 f = ((const float4*)lg)[(size_t)q * NQUAD + quad];
            float M = finv(mq[q]);
            ev.x = f2bf(__expf(f.x - M)); ev.y = f2bf(__expf(f.y - M));
            ev.z = f2bf(__expf(f.z - M)); ev.w = f2bf(__expf(f.w - M));
            lv.x = f2bf(f.x); lv.y = f2bf(f.y);
            lv.z = f2bf(f.z); lv.w = f2bf(f.w);
        }
        epk[(size_t)q * PKQ + quad] = ev;
        lpk[(size_t)q * PKQ + quad] = lv;
    }
}

// ---------------------------------------------------------------- kernel D
// Block = (clause chunk c, event group g). Values for the chunk live in LDS
// (both queues, bf16). Per event: stream the int32 masks for this chunk
// (read exactly once chip-wide), per-wave shfl reduce, store per-wave
// partials -- no barriers inside the event loop.
__global__ __launch_bounds__(256) void emain_kernel(
        const int* __restrict__ pass, const int* __restrict__ good,
        const int* __restrict__ qidx,
        const ushort4* __restrict__ epk, const ushort4* __restrict__ lpk,
        float4* __restrict__ acc) {
    int c = blockIdx.x % NCHUNK;
    int g = blockIdx.x / NCHUNK;
    int tid  = threadIdx.x;
    int w    = tid >> 6;
    int lane = tid & 63;

    __shared__ ushort4 eL[2][CHUNKQ];   // 20.5 KB
    __shared__ ushort4 lL[2][CHUNKQ];   // 20.5 KB
    for (int i = tid; i < 2 * CHUNKQ; i += 256) {
        int q = (i >= CHUNKQ) ? 1 : 0;
        int j = i - q * CHUNKQ;
        eL[q][j] = epk[(size_t)q * PKQ + c * CHUNKQ + j];
        lL[q][j] = lpk[(size_t)q * PKQ + c * CHUNKQ + j];
    }
    __syncthreads();

    int lbase = w * 320 + lane;          // local quad base, iters += 64
    for (int e = 0; e < EVG; e++) {
        int t = g * EVG + e;
        if (t >= T_SEL) break;
        int q = qidx[t] & 1;
        const int4* prow = (const int4*)pass + (size_t)t * NQUAD + c * CHUNKQ;
        const int4* grow = (const int4*)good + (size_t)t * NQUAD + c * CHUNKQ;

        float s = 0.f, sg = 0.f;
        int np = 0, ng = 0;
        #pragma unroll
        for (int it = 0; it < 5; it++) {
            int lq = lbase + it * 64;
            bool ok = (c * CHUNKQ + lq) < NQUAD;
            int4 p  = ok ? prow[lq] : make_int4(0, 0, 0, 0);
            int4 gm = ok ? grow[lq] : make_int4(0, 0, 0, 0);
            ushort4 ev = eL[q][lq];
            ushort4 lv = lL[q][lq];
            np += p.x + p.y + p.z + p.w;
            ng += gm.x + gm.y + gm.z + gm.w;
            s  = fmaf((float)p.x,  b2f(ev.x), s);
            s  = fmaf((float)p.y,  b2f(ev.y), s);
            s  = fmaf((float)p.z,  b2f(ev.z), s);
            s  = fmaf((float)p.w,  b2f(ev.w), s);
            sg = fmaf((float)gm.x, b2f(lv.x), sg);
            sg = fmaf((float)gm.y, b2f(lv.y), sg);
            sg = fmaf((float)gm.z, b2f(lv.z), sg);
            sg = fmaf((float)gm.w, b2f(lv.w), sg);
        }
        for (int off = 32; off; off >>= 1) {
            s  += __shfl_xor(s, off);
            sg += __shfl_xor(sg, off);
            np += __shfl_xor(np, off);
            ng += __shfl_xor(ng, off);
        }
        if (lane == 0)
            acc[((size_t)t * NCHUNK + c) * 4 + w] =
                make_float4(s, sg, (float)np, (float)ng);
    }
}

// ---------------------------------------------------------------- kernel E
__global__ __launch_bounds__(1024) void final_kernel(
        const int* __restrict__ qidx, const float4* __restrict__ acc,
        const unsigned* __restrict__ mq, float* __restrict__ out) {
    int t = threadIdx.x;
    float s = 0.f, sg = 0.f, np = 0.f, ng = 0.f;
    int q = 0;
    if (t < T_SEL) {
        #pragma unroll 2
        for (int c = 0; c < NCHUNK; c++)
            #pragma unroll
            for (int w = 0; w < 4; w++) {
                float4 a = acc[((size_t)t * NCHUNK + c) * 4 + w];
                s += a.x; sg += a.y; np += a.z; ng += a.w;
            }
        q = qidx[t] & 1;
    }
    float M  = finv(mq[q]);
    float nb = np - ng;
    int valid = (t < T_SEL) && (ng > 0.5f) && (nb > 0.5f);

    __shared__ int sc[1024];
    sc[t] = valid;
    __syncthreads();
    for (int off = 1; off < 1024; off <<= 1) {
        int v = (t >= off) ? sc[t - off] : 0;
        __syncthreads();
        sc[t] += v;
        __syncthreads();
    }
    int sb    = sc[t] - valid;          // exclusive scan
    int steps = sc[1023];               // total valid count

    float ce   = logf(s) + M - sg / fmaxf(ng, 1.0f);
    float wgt  = powf(0.995f, (float)sb) * nb / fmaxf(np, 1.0f);
    float term = valid ? wgt * ce : 0.0f;

    __shared__ float sf[1024];
    sf[t] = term;
    __syncthreads();
    for (int off = 512; off; off >>= 1) {
        if (t < off) sf[t] += sf[t + off];
        __syncthreads();
    }
    if (t == 0) out[0] = sf[0] / fmaxf((float)steps, 1.0f);
}

extern "C" void kernel_launch(void* const* d_in, const int* in_sizes, int n_in,
                              void* d_out, int out_size, void* d_ws, size_t ws_size,
                              hipStream_t stream) {
    const float* X     = (const float*)d_in[0];
    const float* W1    = (const float*)d_in[1];
    const float* b1    = (const float*)d_in[2];
    const float* W2    = (const float*)d_in[3];
    const float* b2    = (const float*)d_in[4];
    const float* keysW = (const float*)d_in[5];
    const int*   pass  = (const int*)d_in[6];   // bool -> int32, one per clause
    const int*   good  = (const int*)d_in[7];
    const int*   qidx  = (const int*)d_in[8];

    float*    ws  = (float*)d_ws;
    float*    wk  = ws + WK_OFF;
    float*    ck  = ws + CK_OFF;
    unsigned* mq  = (unsigned*)(ws + MQ_OFF);
    float*    P   = ws + P_OFF;
    float*    lg  = ws + LG_OFF;
    ushort4*  epk = (ushort4*)(ws + EPK_OFF);
    ushort4*  lpk = (ushort4*)(ws + LPK_OFF);
    float4*   acc = (float4*)(ws + ACC_OFF);
    float*    out = (float*)d_out;

    hipLaunchKernelGGL(prep_kernel, dim3(1), dim3(256), 0, stream,
                       W2, b2, keysW, wk, ck, mq);
    hipLaunchKernelGGL(mlp_kernel, dim3(NBLK * JSPLIT), dim3(64), 0, stream,
                       X, W1, b1, wk, P);
    hipLaunchKernelGGL(logits_fin, dim3((N_CL + 255) / 256), dim3(256), 0, stream,
                       P, ck, lg, mq);
    hipLaunchKernelGGL(epack_kernel, dim3(PKQ / 256), dim3(256), 0, stream,
                       lg, mq, epk, lpk);
    hipLaunchKernelGGL(emain_kernel, dim3(NCHUNK * NEG), dim3(256), 0, stream,
                       pass, good, qidx, epk, lpk, acc);
    hipLaunchKernelGGL(final_kernel, dim3(1), dim3(1024), 0, stream,
                       qidx, acc, mq, out);
}

// Round 7
// 151.074 us; speedup vs baseline: 1.3184x; 1.3184x over previous
//
#include <hip/hip_runtime.h>
#include <hip/hip_bf16.h>

#define N_CL   50000
#define FEAT   64
#define HID    256
#define KD     256
#define T_SEL  1000
#define NBLK   782                 // ceil(50000/64) clause groups
#define JSPLIT 4                   // hidden-quarter blocks per clause group (R4-proven)

#define NQUAD  12500               // N_CL/4 quads per mask row (exact)
#define DC     5                   // blocks per (event, role)
#define QPB    2500                // quads per block (DC*QPB == NQUAD)

// ws layout (floats). Event-phase tables OVERLAY P (dead after logits_fin).
// Sizes: ushort4[2][NQUAD] = 2*NQUAD*8 B = 50000 floats (NOT 25000 -- R6 bug).
#define WK_OFF   0                           // 256*2 folded weights
#define CK_OFF   512                         // 2 bias constants
#define MQ_OFF   514                         // 2 uint max-keys
#define P_OFF    520                         // JSPLIT*2*N_CL partial logits (400000)
#define LG_OFF   (P_OFF + JSPLIT * 2 * N_CL) // 2*N_CL final logits f32 (100000)
#define ETAB_OFF 520                         // ushort4[2][NQUAD] exp table   (50000 f)
#define LTAB_OFF (ETAB_OFF + 4 * NQUAD)      // ushort4[2][NQUAD] logit table (50000 f)
#define ACC_OFF  (LTAB_OFF + 4 * NQUAD)      // float2[T_SEL][2][DC][4]       (80000 f)
// overlay ends at 520+180000 << P end (400520); lg untouched.

__device__ __forceinline__ unsigned fkey(float f) {
    unsigned u = __float_as_uint(f);
    return (u & 0x80000000u) ? ~u : (u | 0x80000000u);   // monotone float->uint
}
__device__ __forceinline__ float finv(unsigned k) {
    unsigned u = (k & 0x80000000u) ? (k ^ 0x80000000u) : ~k;
    return __uint_as_float(u);
}
__device__ __forceinline__ float b2f(unsigned short u) {
    return __uint_as_float(((unsigned)u) << 16);
}
__device__ __forceinline__ unsigned short f2bf(float f) {   // RNE bf16 pack
    unsigned u = __float_as_uint(f);
    return (unsigned short)((u + 0x7FFFu + ((u >> 16) & 1u)) >> 16);
}

// ---------------------------------------------------------------- kernel A
__global__ __launch_bounds__(256) void prep_kernel(
        const float* __restrict__ W2, const float* __restrict__ b2,
        const float* __restrict__ keysW,
        float* __restrict__ wk, float* __restrict__ ck,
        unsigned* __restrict__ mq) {
    __shared__ float sk0[KD], sk1[KD], sb2[KD], red[256];
    int tid = threadIdx.x;
    sk0[tid] = keysW[tid];
    sk1[tid] = keysW[KD + tid];
    sb2[tid] = b2[tid];
    if (tid < 2) mq[tid] = 0u;
    __syncthreads();

    const float* w2r = W2 + (size_t)tid * KD;
    float a0 = 0.f, a1 = 0.f;
    #pragma unroll 4
    for (int k = 0; k < KD; k++) {
        float w = w2r[k];
        a0 = fmaf(w, sk0[k], a0);
        a1 = fmaf(w, sk1[k], a1);
    }
    wk[tid * 2 + 0] = a0;
    wk[tid * 2 + 1] = a1;

    red[tid] = sk0[tid] * sb2[tid];
    __syncthreads();
    for (int s = 128; s > 0; s >>= 1) { if (tid < s) red[tid] += red[tid + s]; __syncthreads(); }
    if (tid == 0) ck[0] = red[0];
    __syncthreads();
    red[tid] = sk1[tid] * sb2[tid];
    __syncthreads();
    for (int s = 128; s > 0; s >>= 1) { if (tid < s) red[tid] += red[tid + s]; __syncthreads(); }
    if (tid == 0) ck[1] = red[0];
}

// ---------------------------------------------------------------- kernel B
// MLP partial logits (R4-proven). k-loop FULLY unrolled -> x[] in VGPRs.
__global__ __launch_bounds__(64, 2) void mlp_kernel(
        const float* __restrict__ X, const float* __restrict__ W1,
        const float* __restrict__ b1, const float* __restrict__ wk,
        float* __restrict__ P) {
    int nb = blockIdx.x >> 2;       // p adjacent: 4 blocks sharing X rows
    int p  = blockIdx.x & 3;
    int n  = nb * 64 + threadIdx.x;
    int nc = (n < N_CL) ? n : (N_CL - 1);

    float x[FEAT];
    const float4* xp = (const float4*)(X + (size_t)nc * FEAT);
    #pragma unroll
    for (int k4 = 0; k4 < FEAT / 4; k4++) {
        float4 v = xp[k4];
        x[4 * k4 + 0] = v.x; x[4 * k4 + 1] = v.y;
        x[4 * k4 + 2] = v.z; x[4 * k4 + 3] = v.w;
    }

    float l0 = 0.f, l1 = 0.f;
    int j0 = p * 64;
    for (int jg = 0; jg < 64; jg += 16) {   // runtime loop: h indexed by u only
        float h[16];
        #pragma unroll
        for (int u = 0; u < 16; u++) h[u] = b1[j0 + jg + u];
        #pragma unroll
        for (int k = 0; k < FEAT; k++) {    // FULL unroll: x[k] static
            const float* w1r = W1 + (size_t)k * HID + j0 + jg;
            float xv = x[k];
            #pragma unroll
            for (int u = 0; u < 16; u++) h[u] = fmaf(xv, w1r[u], h[u]);
        }
        #pragma unroll
        for (int u = 0; u < 16; u++) {
            float hv = fmaxf(h[u], 0.0f);
            l0 = fmaf(hv, wk[(j0 + jg + u) * 2 + 0], l0);
            l1 = fmaf(hv, wk[(j0 + jg + u) * 2 + 1], l1);
        }
    }
    if (n < N_CL) {
        P[((size_t)p * 2 + 0) * N_CL + n] = l0;
        P[((size_t)p * 2 + 1) * N_CL + n] = l1;
    }
}

// ---------------------------------------------------------------- kernel C
__global__ __launch_bounds__(256) void logits_fin(
        const float* __restrict__ P, const float* __restrict__ ck,
        float* __restrict__ lg, unsigned* __restrict__ mq) {
    int n = blockIdx.x * 256 + threadIdx.x;
    float m0 = -1e30f, m1 = -1e30f;
    if (n < N_CL) {
        float l0 = ck[0], l1 = ck[1];
        #pragma unroll
        for (int p = 0; p < JSPLIT; p++) {
            l0 += P[((size_t)p * 2 + 0) * N_CL + n];
            l1 += P[((size_t)p * 2 + 1) * N_CL + n];
        }
        lg[n]        = l0;
        lg[N_CL + n] = l1;
        m0 = l0; m1 = l1;
    }
    for (int off = 32; off; off >>= 1) {
        m0 = fmaxf(m0, __shfl_xor(m0, off));
        m1 = fmaxf(m1, __shfl_xor(m1, off));
    }
    __shared__ float sm0[4], sm1[4];
    int w = threadIdx.x >> 6;
    if ((threadIdx.x & 63) == 0) { sm0[w] = m0; sm1[w] = m1; }
    __syncthreads();
    if (threadIdx.x == 0) {
        m0 = fmaxf(fmaxf(sm0[0], sm0[1]), fmaxf(sm0[2], sm0[3]));
        m1 = fmaxf(fmaxf(sm1[0], sm1[1]), fmaxf(sm1[2], sm1[3]));
        atomicMax(mq + 0, fkey(m0));
        atomicMax(mq + 1, fkey(m1));
    }
}

// ---------------------------------------------------------------- kernel C2
// Pack e=exp(l-M) and l as bf16 ushort4 tables (200KB each, L2-resident).
__global__ __launch_bounds__(256) void epack_kernel(
        const float* __restrict__ lg, const unsigned* __restrict__ mq,
        ushort4* __restrict__ etab, ushort4* __restrict__ ltab) {
    int quad = blockIdx.x * 256 + threadIdx.x;
    if (quad >= NQUAD) return;
    #pragma unroll
    for (int q = 0; q < 2; q++) {
        float4 f = ((const float4*)lg)[(size_t)q * NQUAD + quad];
        float M = finv(mq[q]);
        ushort4 ev, lv;
        ev.x = f2bf(__expf(f.x - M)); ev.y = f2bf(__expf(f.y - M));
        ev.z = f2bf(__expf(f.z - M)); ev.w = f2bf(__expf(f.w - M));
        lv.x = f2bf(f.x); lv.y = f2bf(f.y);
        lv.z = f2bf(f.z); lv.w = f2bf(f.w);
        etab[(size_t)q * NQUAD + quad] = ev;
        ltab[(size_t)q * NQUAD + quad] = lv;
    }
}

// ---------------------------------------------------------------- kernel D
// Block = (event t, role, slice c). Role 0 streams pass -> (s, np);
// role 1 streams good -> (sg, ng). One mask stream + one hot L2 table per
// block; explicit 2-stage pipeline; no atomics; per-wave partial stores.
__global__ __launch_bounds__(256) void emain_kernel(
        const int* __restrict__ pass, const int* __restrict__ good,
        const int* __restrict__ qidx,
        const ushort4* __restrict__ etab, const ushort4* __restrict__ ltab,
        float2* __restrict__ acc) {
    int bid  = blockIdx.x;
    int c    = bid % DC;
    int role = (bid / DC) & 1;
    int t    = bid / (2 * DC);
    int tid  = threadIdx.x;
    int q    = qidx[t] & 1;

    const int4*    mrow = (const int4*)(role ? good : pass) + (size_t)t * NQUAD;
    const ushort4* vtab = (role ? ltab : etab) + (size_t)q * NQUAD;

    float s = 0.f;
    int   n = 0;
    int i   = c * QPB + tid;
    const int end = (c + 1) * QPB;

    int4 m; ushort4 v;
    bool have = (i < end);
    if (have) { m = mrow[i]; v = vtab[i]; }
    #pragma unroll 2
    while (have) {
        int i2 = i + 256;
        bool have2 = (i2 < end);
        int4 m2; ushort4 v2;
        if (have2) { m2 = mrow[i2]; v2 = vtab[i2]; }
        n += m.x + m.y + m.z + m.w;
        s += m.x ? b2f(v.x) : 0.0f;
        s += m.y ? b2f(v.y) : 0.0f;
        s += m.z ? b2f(v.z) : 0.0f;
        s += m.w ? b2f(v.w) : 0.0f;
        m = m2; v = v2; i = i2; have = have2;
    }

    for (int off = 32; off; off >>= 1) {
        s += __shfl_xor(s, off);
        n += __shfl_xor(n, off);
    }
    if ((tid & 63) == 0)
        acc[(((size_t)t * 2 + role) * DC + c) * 4 + (tid >> 6)] =
            make_float2(s, (float)n);
}

// ---------------------------------------------------------------- kernel E
__global__ __launch_bounds__(1024) void final_kernel(
        const int* __restrict__ qidx, const float2* __restrict__ acc,
        const unsigned* __restrict__ mq, float* __restrict__ out) {
    int t = threadIdx.x;
    float s = 0.f, sg = 0.f, np = 0.f, ng = 0.f;
    int q = 0;
    if (t < T_SEL) {
        #pragma unroll 5
        for (int c = 0; c < DC; c++)
            #pragma unroll
            for (int w = 0; w < 4; w++) {
                float2 a = acc[(((size_t)t * 2 + 0) * DC + c) * 4 + w];
                float2 b = acc[(((size_t)t * 2 + 1) * DC + c) * 4 + w];
                s += a.x; np += a.y;
                sg += b.x; ng += b.y;
            }
        q = qidx[t] & 1;
    }
    float M  = finv(mq[q]);
    float nb = np - ng;
    int valid = (t < T_SEL) && (ng > 0.5f) && (nb > 0.5f);

    __shared__ int sc[1024];
    sc[t] = valid;
    __syncthreads();
    for (int off = 1; off < 1024; off <<= 1) {
        int v = (t >= off) ? sc[t - off] : 0;
        __syncthreads();
        sc[t] += v;
        __syncthreads();
    }
    int sb    = sc[t] - valid;          // exclusive scan
    int steps = sc[1023];               // total valid count

    float ce   = logf(s) + M - sg / fmaxf(ng, 1.0f);
    float wgt  = powf(0.995f, (float)sb) * nb / fmaxf(np, 1.0f);
    float term = valid ? wgt * ce : 0.0f;

    __shared__ float sf[1024];
    sf[t] = term;
    __syncthreads();
    for (int off = 512; off; off >>= 1) {
        if (t < off) sf[t] += sf[t + off];
        __syncthreads();
    }
    if (t == 0) out[0] = sf[0] / fmaxf((float)steps, 1.0f);
}

extern "C" void kernel_launch(void* const* d_in, const int* in_sizes, int n_in,
                              void* d_out, int out_size, void* d_ws, size_t ws_size,
                              hipStream_t stream) {
    const float* X     = (const float*)d_in[0];
    const float* W1    = (const float*)d_in[1];
    const float* b1    = (const float*)d_in[2];
    const float* W2    = (const float*)d_in[3];
    const float* b2    = (const float*)d_in[4];
    const float* keysW = (const float*)d_in[5];
    const int*   pass  = (const int*)d_in[6];   // bool -> int32, one per clause
    const int*   good  = (const int*)d_in[7];
    const int*   qidx  = (const int*)d_in[8];

    float*    ws   = (float*)d_ws;
    float*    wk   = ws + WK_OFF;
    float*    ck   = ws + CK_OFF;
    unsigned* mq   = (unsigned*)(ws + MQ_OFF);
    float*    P    = ws + P_OFF;
    float*    lg   = ws + LG_OFF;
    ushort4*  etab = (ushort4*)(ws + ETAB_OFF);   // overlays P (dead)
    ushort4*  ltab = (ushort4*)(ws + LTAB_OFF);   // overlays P (dead)
    float2*   acc  = (float2*)(ws + ACC_OFF);     // overlays P (dead)
    float*    out  = (float*)d_out;

    hipLaunchKernelGGL(prep_kernel, dim3(1), dim3(256), 0, stream,
                       W2, b2, keysW, wk, ck, mq);
    hipLaunchKernelGGL(mlp_kernel, dim3(NBLK * JSPLIT), dim3(64), 0, stream,
                       X, W1, b1, wk, P);
    hipLaunchKernelGGL(logits_fin, dim3((N_CL + 255) / 256), dim3(256), 0, stream,
                       P, ck, lg, mq);
    hipLaunchKernelGGL(epack_kernel, dim3((NQUAD + 255) / 256), dim3(256), 0, stream,
                       lg, mq, etab, ltab);
    hipLaunchKernelGGL(emain_kernel, dim3(T_SEL * 2 * DC), dim3(256), 0, stream,
                       pass, good, qidx, etab, ltab, acc);
    hipLaunchKernelGGL(final_kernel, dim3(1), dim3(1024), 0, stream,
                       qidx, acc, mq, out);
}